// Round 2
// baseline (26.427 us; speedup 1.0000x reference)
//
#include <hip/hip_runtime.h>
#include <math.h>

#define KACC 10
#define CH 16   // rows prefetched per chunk (B=64 -> 4 chunks max, ~1 typical)

__global__ __launch_bounds__(256)
void sss_kernel(const float* __restrict__ Z, const float* __restrict__ U,
                const float* __restrict__ uu, const float* __restrict__ ga,
                const float* __restrict__ la, float* __restrict__ out,
                int P, int B, int K)
{
#pragma clang fp contract(off)
    int p = blockIdx.x * blockDim.x + threadIdx.x;
    if (p >= P) return;

    const float g      = ga[p];
    const float lalpha = la[p];

    // --- MarsagliaTsampler per-column constants ---
    const float alpha = fmaxf(g, 0.0f) + 1.0f;     // relu + 1
    const float d     = alpha - (1.0f / 3.0f);
    const float c     = 1.0f / sqrtf(9.0f * d);
    const float neg_inv_c = -(1.0f / c);

    // --- rejection scan: first K accepted samples down the rows ---
    // th[] kept strictly register-resident: static indices only (select chain).
    float th[KACC];
#pragma unroll
    for (int k = 0; k < KACC; ++k) th[k] = 0.0f;

    int cnt = 0;
    for (int base = 0; base + CH <= B; base += CH) {
        // issue all 2*CH loads up front (independent addresses -> MLP)
        float zv[CH], wv[CH];
#pragma unroll
        for (int i = 0; i < CH; ++i) {
            const size_t off = (size_t)(base + i) * (size_t)P + (size_t)p;
            zv[i] = Z[off];
            wv[i] = U[off];
        }
#pragma unroll
        for (int i = 0; i < CH; ++i) {
            float z  = zv[i];
            float Uv = wv[i];
            float t  = 1.0f + c * z;
            float V  = (t * t) * t;                // (1+cZ)**3
            // ((0.5*Z^2 + d) - d*V) + d*log(V); log(V<=0) -> NaN -> false
            float rhs = ((0.5f * (z * z) + d) - d * V) + d * logf(V);
            bool acc = (z > neg_inv_c) && (logf(Uv) < rhs) && (cnt < KACC);
            float val = d * V;
#pragma unroll
            for (int k = 0; k < KACC; ++k)
                th[k] = (acc && cnt == k) ? val : th[k];
            cnt += acc ? 1 : 0;
        }
        if (cnt >= KACC) break;   // chunk-boundary exit only (keeps loads batched)
    }

    // --- output layout: z[K,P], z_mean[P], theta[K,P], alpha[P], logalpha[P] ---
    const size_t KP = (size_t)K * (size_t)P;
    float* o_z        = out;
    float* o_zmean    = out + KP;
    float* o_theta    = out + KP + (size_t)P;
    float* o_alpha    = out + 2 * KP + (size_t)P;
    float* o_logalpha = out + 2 * KP + 2 * (size_t)P;

#pragma unroll
    for (int k = 0; k < KACC; ++k)
        o_theta[(size_t)k * (size_t)P + (size_t)p] = th[k];

    // --- hard-concrete gate ---
    const float SHIFT = (float)(2.0 / 3.0 * (0.1 / 1.1)); // BETA * (-GAMMA/ZETA)
    float xm = lalpha - SHIFT;
    float zm = 1.0f / (1.0f + expf(-xm));

#pragma unroll
    for (int k = 0; k < KACC; ++k) {
        float uv = uu[(size_t)k * (size_t)P + (size_t)p];
        float x = ((logf(uv) - log1pf(-uv)) + lalpha) / (2.0f / 3.0f);
        float s = 1.0f / (1.0f + expf(-x));
        float zz = 1.2f * s + (-0.1f);
        zz = fminf(fmaxf(zz, 0.0f), 1.0f);
        o_z[(size_t)k * (size_t)P + (size_t)p] = zz;
    }

    o_zmean[p]    = zm;
    o_alpha[p]    = alpha;
    o_logalpha[p] = lalpha;
}

extern "C" void kernel_launch(void* const* d_in, const int* in_sizes, int n_in,
                              void* d_out, int out_size, void* d_ws, size_t ws_size,
                              hipStream_t stream) {
    const float* Z  = (const float*)d_in[0];
    const float* U  = (const float*)d_in[1];
    const float* uu = (const float*)d_in[2];
    const float* ga = (const float*)d_in[3];
    const float* la = (const float*)d_in[4];
    float* out = (float*)d_out;

    const int P = in_sizes[3];            // gamma_alpha is [P]
    const int B = in_sizes[0] / P;        // Z is [B,P]
    const int K = in_sizes[2] / P;        // u is [K,P]

    const int block = 256;
    const int grid  = (P + block - 1) / block;
    sss_kernel<<<grid, block, 0, stream>>>(Z, U, uu, ga, la, out, P, B, K);
}

// Round 3
// 19.635 us; speedup vs baseline: 1.3459x; 1.3459x over previous
//
#include <hip/hip_runtime.h>
#include <math.h>

#define KACC 10
#define CH1 12   // first chunk rows (covers >99.8% of columns)
#define CH2 8    // continuation chunk rows

__global__ __launch_bounds__(256)
void sss_kernel(const float* __restrict__ Z, const float* __restrict__ U,
                const float* __restrict__ uu, const float* __restrict__ ga,
                const float* __restrict__ la, float* __restrict__ out,
                int P, int B, int K, int nbScan)
{
#pragma clang fp contract(off)
    const size_t KP = (size_t)K * (size_t)P;
    float* o_z        = out;
    float* o_zmean    = out + KP;
    float* o_theta    = out + KP + (size_t)P;
    float* o_alpha    = out + 2 * KP + (size_t)P;
    float* o_logalpha = out + 2 * KP + 2 * (size_t)P;

    const int bid = blockIdx.x;

    if (bid < nbScan) {
        // ---------------- SCAN ROLE: Marsaglia-Tsang first-K compaction ----------------
        const int p = bid * blockDim.x + threadIdx.x;
        if (p >= P) return;

        const float g      = ga[p];
        const float lalpha = la[p];

        const float alpha = fmaxf(g, 0.0f) + 1.0f;     // relu + 1
        const float d     = alpha - (1.0f / 3.0f);
        const float c     = 1.0f / sqrtf(9.0f * d);
        const float neg_inv_c = -(1.0f / c);

        float th[KACC];
#pragma unroll
        for (int k = 0; k < KACC; ++k) th[k] = 0.0f;
        int cnt = 0;

        // chunk 1: rows 0..CH1-1, all loads issued up front (MLP)
        {
            float zv[CH1], wv[CH1];
#pragma unroll
            for (int i = 0; i < CH1; ++i) {
                const size_t off = (size_t)i * (size_t)P + (size_t)p;
                zv[i] = Z[off];
                wv[i] = U[off];
            }
#pragma unroll
            for (int i = 0; i < CH1; ++i) {
                float z  = zv[i];
                float Uv = wv[i];
                float t  = 1.0f + c * z;
                float V  = (t * t) * t;                // (1+cZ)**3
                float rhs = ((0.5f * (z * z) + d) - d * V) + d * logf(V);
                bool acc = (z > neg_inv_c) && (logf(Uv) < rhs) && (cnt < KACC);
                float val = d * V;
#pragma unroll
                for (int k = 0; k < KACC; ++k)
                    th[k] = (acc && cnt == k) ? val : th[k];
                cnt += acc ? 1 : 0;
            }
        }

        // rare continuation (per-lane masked by the break)
        if (cnt < KACC) {
            for (int base = CH1; base < B; base += CH2) {
                float zv[CH2], wv[CH2];
#pragma unroll
                for (int i = 0; i < CH2; ++i) {
                    const int r = base + i;            // wave-uniform bound check
                    const size_t off = (size_t)r * (size_t)P + (size_t)p;
                    zv[i] = (r < B) ? Z[off] : __int_as_float(0x7fc00000); // NaN -> reject
                    wv[i] = (r < B) ? U[off] : 1.0f;
                }
#pragma unroll
                for (int i = 0; i < CH2; ++i) {
                    float z  = zv[i];
                    float Uv = wv[i];
                    float t  = 1.0f + c * z;
                    float V  = (t * t) * t;
                    float rhs = ((0.5f * (z * z) + d) - d * V) + d * logf(V);
                    bool acc = (z > neg_inv_c) && (logf(Uv) < rhs) && (cnt < KACC);
                    float val = d * V;
#pragma unroll
                    for (int k = 0; k < KACC; ++k)
                        th[k] = (acc && cnt == k) ? val : th[k];
                    cnt += acc ? 1 : 0;
                }
                if (cnt >= KACC) break;
            }
        }

#pragma unroll
        for (int k = 0; k < KACC; ++k)
            o_theta[(size_t)k * (size_t)P + (size_t)p] = th[k];
        o_alpha[p]    = alpha;
        o_logalpha[p] = lalpha;

    } else {
        // ---------------- GATE ROLE: hard-concrete z + z_mean ----------------
        const int p = (bid - nbScan) * blockDim.x + threadIdx.x;
        if (p >= P) return;

        const float lalpha = la[p];

        float uv[KACC];
#pragma unroll
        for (int k = 0; k < KACC; ++k)
            uv[k] = uu[(size_t)k * (size_t)P + (size_t)p];

        const float SHIFT = 0.060606062f;              // BETA * (-GAMMA/ZETA)
        float zm = 1.0f / (1.0f + __expf(-(lalpha - SHIFT)));

#pragma unroll
        for (int k = 0; k < KACC; ++k) {
            float u = uv[k];
            // s = sigmoid((log u - log1p(-u) + la) / (2/3)); native-precision is
            // safe: non-saturated z needs u in (0.07, 0.65) where 1-u is exact.
            float x = ((__logf(u) - __logf(1.0f - u)) + lalpha) * 1.5f;
            float s = 1.0f / (1.0f + __expf(-x));
            float zz = 1.2f * s - 0.1f;
            zz = fminf(fmaxf(zz, 0.0f), 1.0f);
            o_z[(size_t)k * (size_t)P + (size_t)p] = zz;
        }
        o_zmean[p] = zm;
    }
}

extern "C" void kernel_launch(void* const* d_in, const int* in_sizes, int n_in,
                              void* d_out, int out_size, void* d_ws, size_t ws_size,
                              hipStream_t stream) {
    const float* Z  = (const float*)d_in[0];
    const float* U  = (const float*)d_in[1];
    const float* uu = (const float*)d_in[2];
    const float* ga = (const float*)d_in[3];
    const float* la = (const float*)d_in[4];
    float* out = (float*)d_out;

    const int P = in_sizes[3];            // gamma_alpha is [P]
    const int B = in_sizes[0] / P;        // Z is [B,P]
    const int K = in_sizes[2] / P;        // u is [K,P]

    const int block  = 256;
    const int nbScan = (P + block - 1) / block;
    const int grid   = 2 * nbScan;        // first half scans, second half gates
    sss_kernel<<<grid, block, 0, stream>>>(Z, U, uu, ga, la, out, P, B, K, nbScan);
}